// Round 1
// baseline (1901.734 us; speedup 1.0000x reference)
//
#include <hip/hip_runtime.h>
#include <math.h>

#define NB   8192
#define TLEN 100
#define SEQ  101
#define DE   36
#define DM   72
#define LDST 81   // LDS row stride (odd -> no power-of-2 bank aliasing)

struct Params {
  const float *history; const int *ts; const int *target_ts; const int *task;
  const float *w_np; const float *b_np; const float *w_wp; const float *b_wp;
  const float *task_emb;
  const float *tw1[2]; const float *tb1[2]; const float *tw2[2]; const float *tb2[2];
  const float *cw1[2]; const float *cb1[2]; const float *cw2[2]; const float *cb2[2];
  const float *wp_time; const float *bp_time; const float *w_head; const float *b_head;
  float *out;
};

__global__ __launch_bounds__(256, 2) void fpfn_kernel(Params p) {
  __shared__ float xs[SEQ * LDST];   // x tile (101 x 72, stride 81)
  __shared__ float yb[SEQ * LDST];   // intermediate (y1: 72x72, y2: 101x72)
  __shared__ float pe[640];          // pos tables: pe_y[0,88) pe_m[88,192) pe_d[192,576) pe_w[576,640)
  __shared__ float red[256];
  __shared__ float sh[TLEN];         // scaled history
  __shared__ int   dates[TLEN * 4];  // pre-scaled table row offsets per t

  const int tid = threadIdx.x;
  const int b  = blockIdx.x;
  const int tx = tid & 15;
  const int ty = tid >> 4;

  // ---- positional tables (identical for all blocks; cheap) ----
  for (int idx = tid; idx < 640; idx += 256) {
    int periods, freqs, row, col;
    if (idx < 88)       { periods = 10; freqs = 4; row = idx >> 3;        col = idx & 7; }
    else if (idx < 192) { periods = 12; freqs = 4; row = (idx - 88) >> 3; col = (idx - 88) & 7; }
    else if (idx < 576) { periods = 31; freqs = 6; int r2 = idx - 192; row = r2 / 12; col = r2 - row * 12; }
    else                { periods = 7;  freqs = 4; row = (idx - 576) >> 3; col = (idx - 576) & 7; }
    int jf = (col < freqs) ? col : (col - freqs);
    float pip = (float)(3.14159265358979323846 / (double)periods);
    float ang = pip * (float)(1 << jf) * ((float)row - 1.0f);
    pe[idx] = (col < freqs) ? sinf(ang) : cosf(ang);
  }

  auto blockReduce = [&](float v) -> float {
    red[tid] = v;
    __syncthreads();
    #pragma unroll
    for (int s = 128; s > 0; s >>= 1) {
      if (tid < s) red[tid] += red[tid + s];
      __syncthreads();
    }
    float r = red[0];
    __syncthreads();
    return r;
  };

  // ---- robust_scale (exact reference semantics) ----
  float h  = (tid < TLEN) ? p.history[(size_t)b * TLEN + tid] : 0.f;
  float nz = (tid < TLEN && h != 0.f) ? 1.f : 0.f;
  float cnt  = blockReduce(nz);
  float hsum = blockReduce(h);              // zeros contribute 0 -> equals masked sum
  float safe = fmaxf(cnt, 1.f);
  float mean = hsum / safe;
  float var  = blockReduce(nz * (h - mean) * (h - mean)) / safe;
  float mean_z = (cnt > 0.f) ? mean : 0.f;
  float std_z  = (cnt > 0.f) ? sqrtf(var) : 0.f;
  float upper  = mean_z + 2.f * std_z;
  float clipped = fminf(fmaxf(h, 0.f), upper);
  float nz2  = (tid < TLEN && clipped != 0.f) ? 1.f : 0.f;
  float cnt2 = blockReduce(nz2);
  float csum = blockReduce(nz2 * clipped);
  float safe2 = fmaxf(cnt2, 1.f);
  float mc = csum / safe2;
  float vc = blockReduce(nz2 * (clipped - mc) * (clipped - mc)) / safe2;
  float mc_z = (cnt2 > 0.f) ? mc : 0.f;
  float sc_z = (cnt2 > 0.f) ? sqrtf(vc) : 0.f;
  float s = mc_z + sc_z + 1e-4f;
  float hist_mean = hsum * (1.f / (float)TLEN);

  int yr99 = p.ts[((size_t)b * TLEN + (TLEN - 1)) * 4 + 0];
  if (tid < TLEN) {
    sh[tid] = fminf(fmaxf(h / s, 0.f), 3.f);
    const int* tsb = p.ts + ((size_t)b * TLEN + tid) * 4;
    int dy = yr99 - tsb[0]; dy = dy < 0 ? 0 : (dy > 10 ? 10 : dy);
    dates[tid * 4 + 0] = dy * 8;
    dates[tid * 4 + 1] = 88  + tsb[1] * 8;
    dates[tid * 4 + 2] = 192 + tsb[2] * 12;
    dates[tid * 4 + 3] = 576 + tsb[3] * 8;
  }
  __syncthreads();

  // ---- build x (101 x 72) ----
  for (int idx = tid; idx < TLEN * DM; idx += 256) {
    int t = idx / DM;
    int j = idx - t * DM;
    float sv = sh[t];
    float v;
    if (j < DE) {
      v = fmaxf(fmaf(sv, p.w_np[j], p.b_np[j]), 0.f);
    } else {
      int jj = j - DE;
      float e1 = fmaxf(fmaf(sv, p.w_wp[jj], p.b_wp[jj]), 0.f);
      float pv;
      if (jj < 8)       pv = pe[dates[t * 4 + 0] + jj];
      else if (jj < 16) pv = pe[dates[t * 4 + 1] + (jj - 8)];
      else if (jj < 28) pv = pe[dates[t * 4 + 2] + (jj - 16)];
      else              pv = pe[dates[t * 4 + 3] + (jj - 28)];
      v = e1 + pv;
    }
    xs[t * LDST + j] = v;
  }
  if (tid < DM) {  // target row (t = 100)
    int tk = p.task[b];
    float te = p.task_emb[tk * DE + (tid < DE ? tid : tid - DE)];
    float v = te;
    if (tid >= DE) {
      int jj = tid - DE;
      const int* tt = p.target_ts + (size_t)b * 5;
      int dy = yr99 - tt[0]; dy = dy < 0 ? 0 : (dy > 10 ? 10 : dy);
      float qv;
      if (jj < 8)       qv = pe[dy * 8 + jj];
      else if (jj < 16) qv = pe[88  + tt[1] * 8  + (jj - 8)];
      else if (jj < 28) qv = pe[192 + tt[2] * 12 + (jj - 16)];
      else              qv = pe[576 + tt[3] * 8  + (jj - 28)];
      v = te + qv;
    }
    xs[(SEQ - 1) * LDST + tid] = v;
  }
  __syncthreads();

  // per-thread tile indices (clamped variants for safe dead-lane loads)
  int colv[5], colvc[5];
  #pragma unroll
  for (int v = 0; v < 5; ++v) { colv[v] = tx + 16 * v; colvc[v] = colv[v] < DM ? colv[v] : DM - 1; }
  int rowu[7], rowuc[7];
  #pragma unroll
  for (int u = 0; u < 7; ++u) { rowu[u] = ty + 16 * u; rowuc[u] = rowu[u] < SEQ ? rowu[u] : SEQ - 1; }

  // ---- 2 resblocks ----
  for (int r = 0; r < 2; ++r) {
    const float* tw1 = p.tw1[r]; const float* tb1 = p.tb1[r];
    const float* tw2 = p.tw2[r]; const float* tb2 = p.tb2[r];
    const float* cw1 = p.cw1[r]; const float* cb1 = p.cb1[r];
    const float* cw2 = p.cw2[r]; const float* cb2 = p.cb2[r];

    // A: y1[c][j] = relu(tb1[j] + sum_t x[t][c] * tw1[t][j])   (72x72, K=101)
    {
      float acc[5][5];
      #pragma unroll
      for (int u = 0; u < 5; ++u)
        #pragma unroll
        for (int v = 0; v < 5; ++v) acc[u][v] = 0.f;
      for (int t = 0; t < SEQ; ++t) {
        float a[5], w[5];
        #pragma unroll
        for (int u = 0; u < 5; ++u) a[u] = xs[t * LDST + ty + 16 * u];   // col<=79 < LDST, safe
        #pragma unroll
        for (int v = 0; v < 5; ++v) w[v] = tw1[t * DM + colvc[v]];
        #pragma unroll
        for (int u = 0; u < 5; ++u)
          #pragma unroll
          for (int v = 0; v < 5; ++v) acc[u][v] = fmaf(a[u], w[v], acc[u][v]);
      }
      #pragma unroll
      for (int u = 0; u < 5; ++u) {
        int c = ty + 16 * u;
        if (c < DM) {
          #pragma unroll
          for (int v = 0; v < 5; ++v)
            if (colv[v] < DM) yb[c * LDST + colv[v]] = fmaxf(acc[u][v] + tb1[colv[v]], 0.f);
        }
      }
    }
    __syncthreads();

    // B: x[t][c] += tb2[t] + sum_j y1[c][j] * tw2[j][t]   (101x72, K=72)
    {
      float acc[7][5];
      #pragma unroll
      for (int u = 0; u < 7; ++u)
        #pragma unroll
        for (int v = 0; v < 5; ++v) acc[u][v] = 0.f;
      for (int j = 0; j < DM; ++j) {
        float a[5], w[7];
        #pragma unroll
        for (int v = 0; v < 5; ++v) a[v] = yb[colv[v] * LDST + j];      // row<=79 < 101, safe
        #pragma unroll
        for (int u = 0; u < 7; ++u) w[u] = tw2[j * SEQ + rowuc[u]];
        #pragma unroll
        for (int u = 0; u < 7; ++u)
          #pragma unroll
          for (int v = 0; v < 5; ++v) acc[u][v] = fmaf(a[v], w[u], acc[u][v]);
      }
      #pragma unroll
      for (int u = 0; u < 7; ++u) {
        int t = rowu[u];
        if (t < SEQ) {
          float tb2t = tb2[t];
          #pragma unroll
          for (int v = 0; v < 5; ++v)
            if (colv[v] < DM) xs[t * LDST + colv[v]] += acc[u][v] + tb2t;
        }
      }
    }
    __syncthreads();

    // C: y2[t][j] = relu(cb1[j] + sum_c x[t][c] * cw1[c][j])   (101x72, K=72)
    {
      float acc[7][5];
      #pragma unroll
      for (int u = 0; u < 7; ++u)
        #pragma unroll
        for (int v = 0; v < 5; ++v) acc[u][v] = 0.f;
      for (int c = 0; c < DM; ++c) {
        float a[7], w[5];
        #pragma unroll
        for (int u = 0; u < 7; ++u) a[u] = xs[rowuc[u] * LDST + c];
        #pragma unroll
        for (int v = 0; v < 5; ++v) w[v] = cw1[c * DM + colvc[v]];
        #pragma unroll
        for (int u = 0; u < 7; ++u)
          #pragma unroll
          for (int v = 0; v < 5; ++v) acc[u][v] = fmaf(a[u], w[v], acc[u][v]);
      }
      #pragma unroll
      for (int u = 0; u < 7; ++u) {
        int t = rowu[u];
        if (t < SEQ) {
          #pragma unroll
          for (int v = 0; v < 5; ++v)
            if (colv[v] < DM) yb[t * LDST + colv[v]] = fmaxf(acc[u][v] + cb1[colv[v]], 0.f);
        }
      }
    }
    __syncthreads();

    // D: x[t][c] += cb2[c] + sum_j y2[t][j] * cw2[j][c]   (101x72, K=72)
    {
      float acc[7][5];
      #pragma unroll
      for (int u = 0; u < 7; ++u)
        #pragma unroll
        for (int v = 0; v < 5; ++v) acc[u][v] = 0.f;
      for (int j = 0; j < DM; ++j) {
        float a[7], w[5];
        #pragma unroll
        for (int u = 0; u < 7; ++u) a[u] = yb[rowuc[u] * LDST + j];
        #pragma unroll
        for (int v = 0; v < 5; ++v) w[v] = cw2[j * DM + colvc[v]];
        #pragma unroll
        for (int u = 0; u < 7; ++u)
          #pragma unroll
          for (int v = 0; v < 5; ++v) acc[u][v] = fmaf(a[u], w[v], acc[u][v]);
      }
      #pragma unroll
      for (int u = 0; u < 7; ++u) {
        int t = rowu[u];
        if (t < SEQ) {
          #pragma unroll
          for (int v = 0; v < 5; ++v)
            if (colv[v] < DM) xs[t * LDST + colv[v]] += acc[u][v] + cb2[colv[v]];
        }
      }
    }
    __syncthreads();
  }

  // ---- head ----
  if (tid < DM) {
    float acc = 0.f;
    for (int t = 0; t < SEQ; ++t) acc = fmaf(xs[t * LDST + tid], p.wp_time[t], acc);
    red[tid] = (acc + p.bp_time[0]) * p.w_head[tid];
  }
  __syncthreads();
  if (tid == 0) {
    float yv = 0.f;
    #pragma unroll 8
    for (int i = 0; i < DM; ++i) yv += red[i];
    yv = fmaxf(yv + p.b_head[0], 0.f);
    p.out[b]      = yv * s + hist_mean;
    p.out[NB + b] = s;
  }
}

extern "C" void kernel_launch(void* const* d_in, const int* in_sizes, int n_in,
                              void* d_out, int out_size, void* d_ws, size_t ws_size,
                              hipStream_t stream) {
  (void)in_sizes; (void)n_in; (void)out_size; (void)d_ws; (void)ws_size;
  Params p;
  p.history   = (const float*)d_in[0];
  p.ts        = (const int*)  d_in[1];
  p.target_ts = (const int*)  d_in[2];
  p.task      = (const int*)  d_in[3];
  p.w_np = (const float*)d_in[4];  p.b_np = (const float*)d_in[5];
  p.w_wp = (const float*)d_in[6];  p.b_wp = (const float*)d_in[7];
  p.task_emb = (const float*)d_in[8];
  p.tw1[0] = (const float*)d_in[9];  p.tb1[0] = (const float*)d_in[10];
  p.tw2[0] = (const float*)d_in[11]; p.tb2[0] = (const float*)d_in[12];
  p.cw1[0] = (const float*)d_in[13]; p.cb1[0] = (const float*)d_in[14];
  p.cw2[0] = (const float*)d_in[15]; p.cb2[0] = (const float*)d_in[16];
  p.tw1[1] = (const float*)d_in[17]; p.tb1[1] = (const float*)d_in[18];
  p.tw2[1] = (const float*)d_in[19]; p.tb2[1] = (const float*)d_in[20];
  p.cw1[1] = (const float*)d_in[21]; p.cb1[1] = (const float*)d_in[22];
  p.cw2[1] = (const float*)d_in[23]; p.cb2[1] = (const float*)d_in[24];
  p.wp_time = (const float*)d_in[25]; p.bp_time = (const float*)d_in[26];
  p.w_head  = (const float*)d_in[27]; p.b_head  = (const float*)d_in[28];
  p.out = (float*)d_out;
  hipLaunchKernelGGL(fpfn_kernel, dim3(NB), dim3(256), 0, stream, p);
}

// Round 2
// 1780.528 us; speedup vs baseline: 1.0681x; 1.0681x over previous
//
#include <hip/hip_runtime.h>
#include <math.h>

#define NB   8192
#define TLEN 100
#define SEQ  101
#define DE   36
#define DM   72
#define LDX  76    // xs row stride (mult of 4, 76%32=12 -> 2-way max)
#define LDT  104   // xT row stride
#define LDY  76    // y buffer row stride
#define LDWT 104   // tw1T row stride in ws

#define SZ_TW1T (DM*LDWT)
#define SZ_TW2T (SEQ*DM)
#define SZ_CWT  (DM*DM)
#define OFF_TW1T 0
#define OFF_TW2T (OFF_TW1T + 2*SZ_TW1T)
#define OFF_CW1T (OFF_TW2T + 2*SZ_TW2T)
#define OFF_CW2T (OFF_CW1T + 2*SZ_CWT)

#define LD4G(p) (*(const float4*)(p))

struct Params {
  const float *history; const int *ts; const int *target_ts; const int *task;
  const float *w_np; const float *b_np; const float *w_wp; const float *b_wp;
  const float *task_emb;
  const float *tb1[2]; const float *tb2[2]; const float *cb1[2]; const float *cb2[2];
  const float *wp_time; const float *bp_time; const float *w_head; const float *b_head;
  const float *ws; float *out;
};

struct SetupParams {
  const float* tw1[2]; const float* tw2[2]; const float* cw1[2]; const float* cw2[2];
  float* ws;
};

// Transpose all weight matrices once so main-kernel K-loops read contiguous 16B.
__global__ void setup_kernel(SetupParams sp) {
  int idx = blockIdx.x * blockDim.x + threadIdx.x;
  int stride = gridDim.x * blockDim.x;
  for (int r = 0; r < 2; ++r) {
    for (int i = idx; i < SEQ * DM; i += stride) {           // tw1[t][j] -> tw1T[j][t]
      int row = i / DM, col = i - row * DM;
      sp.ws[OFF_TW1T + r * SZ_TW1T + col * LDWT + row] = sp.tw1[r][i];
    }
    for (int i = idx; i < DM * SEQ; i += stride) {           // tw2[j][t] -> tw2T[t][j]
      int row = i / SEQ, col = i - row * SEQ;
      sp.ws[OFF_TW2T + r * SZ_TW2T + col * DM + row] = sp.tw2[r][i];
    }
    for (int i = idx; i < DM * DM; i += stride) {            // cw1[c][j] -> cw1T[j][c]
      int row = i / DM, col = i - row * DM;
      sp.ws[OFF_CW1T + r * SZ_CWT + col * DM + row] = sp.cw1[r][i];
    }
    for (int i = idx; i < DM * DM; i += stride) {            // cw2[j][c] -> cw2T[c][j]
      int row = i / DM, col = i - row * DM;
      sp.ws[OFF_CW2T + r * SZ_CWT + col * DM + row] = sp.cw2[r][i];
    }
  }
}

__global__ __launch_bounds__(256, 2) void fpfn_kernel(Params p) {
  __shared__ __align__(16) float xs[SEQ * LDX];   // x (101 x 72)
  __shared__ __align__(16) float yb[SEQ * LDY];   // xT (72x104=7488) / y1 (72x76) / y2 (101x76); 7676 floats
  __shared__ float pe[640];
  __shared__ float red[256];
  __shared__ float sh[TLEN];
  __shared__ int   dates[TLEN * 4];

  const int tid = threadIdx.x;
  const int b  = blockIdx.x;
  const int tx = tid & 15;
  const int ty = tid >> 4;

  // ---- positional tables ----
  for (int idx = tid; idx < 640; idx += 256) {
    int periods, freqs, row, col;
    if (idx < 88)       { periods = 10; freqs = 4; row = idx >> 3;        col = idx & 7; }
    else if (idx < 192) { periods = 12; freqs = 4; row = (idx - 88) >> 3; col = (idx - 88) & 7; }
    else if (idx < 576) { periods = 31; freqs = 6; int r2 = idx - 192; row = r2 / 12; col = r2 - row * 12; }
    else                { periods = 7;  freqs = 4; row = (idx - 576) >> 3; col = (idx - 576) & 7; }
    int jf = (col < freqs) ? col : (col - freqs);
    float pip = (float)(3.14159265358979323846 / (double)periods);
    float ang = pip * (float)(1 << jf) * ((float)row - 1.0f);
    pe[idx] = (col < freqs) ? sinf(ang) : cosf(ang);
  }

  auto blockReduce = [&](float v) -> float {
    red[tid] = v;
    __syncthreads();
    #pragma unroll
    for (int s = 128; s > 0; s >>= 1) {
      if (tid < s) red[tid] += red[tid + s];
      __syncthreads();
    }
    float r = red[0];
    __syncthreads();
    return r;
  };

  // ---- robust_scale ----
  float h  = (tid < TLEN) ? p.history[(size_t)b * TLEN + tid] : 0.f;
  float nz = (tid < TLEN && h != 0.f) ? 1.f : 0.f;
  float cnt  = blockReduce(nz);
  float hsum = blockReduce(h);
  float safe = fmaxf(cnt, 1.f);
  float mean = hsum / safe;
  float var  = blockReduce(nz * (h - mean) * (h - mean)) / safe;
  float mean_z = (cnt > 0.f) ? mean : 0.f;
  float std_z  = (cnt > 0.f) ? sqrtf(var) : 0.f;
  float upper  = mean_z + 2.f * std_z;
  float clipped = fminf(fmaxf(h, 0.f), upper);
  float nz2  = (tid < TLEN && clipped != 0.f) ? 1.f : 0.f;
  float cnt2 = blockReduce(nz2);
  float csum = blockReduce(nz2 * clipped);
  float safe2 = fmaxf(cnt2, 1.f);
  float mc = csum / safe2;
  float vc = blockReduce(nz2 * (clipped - mc) * (clipped - mc)) / safe2;
  float mc_z = (cnt2 > 0.f) ? mc : 0.f;
  float sc_z = (cnt2 > 0.f) ? sqrtf(vc) : 0.f;
  float s = mc_z + sc_z + 1e-4f;
  float hist_mean = hsum * (1.f / (float)TLEN);

  int yr99 = p.ts[((size_t)b * TLEN + (TLEN - 1)) * 4 + 0];
  if (tid < TLEN) {
    sh[tid] = fminf(fmaxf(h / s, 0.f), 3.f);
    const int* tsb = p.ts + ((size_t)b * TLEN + tid) * 4;
    int dy = yr99 - tsb[0]; dy = dy < 0 ? 0 : (dy > 10 ? 10 : dy);
    dates[tid * 4 + 0] = dy * 8;
    dates[tid * 4 + 1] = 88  + tsb[1] * 8;
    dates[tid * 4 + 2] = 192 + tsb[2] * 12;
    dates[tid * 4 + 3] = 576 + tsb[3] * 8;
  }
  __syncthreads();

  // ---- build x (101 x 72) ----
  for (int idx = tid; idx < TLEN * DM; idx += 256) {
    int t = idx / DM;
    int j = idx - t * DM;
    float sv = sh[t];
    float v;
    if (j < DE) {
      v = fmaxf(fmaf(sv, p.w_np[j], p.b_np[j]), 0.f);
    } else {
      int jj = j - DE;
      float e1 = fmaxf(fmaf(sv, p.w_wp[jj], p.b_wp[jj]), 0.f);
      float pv;
      if (jj < 8)       pv = pe[dates[t * 4 + 0] + jj];
      else if (jj < 16) pv = pe[dates[t * 4 + 1] + (jj - 8)];
      else if (jj < 28) pv = pe[dates[t * 4 + 2] + (jj - 16)];
      else              pv = pe[dates[t * 4 + 3] + (jj - 28)];
      v = e1 + pv;
    }
    xs[t * LDX + j] = v;
  }
  if (tid < DM) {  // target row (t = 100)
    int tk = p.task[b];
    float te = p.task_emb[tk * DE + (tid < DE ? tid : tid - DE)];
    float v = te;
    if (tid >= DE) {
      int jj = tid - DE;
      const int* tt = p.target_ts + (size_t)b * 5;
      int dy = yr99 - tt[0]; dy = dy < 0 ? 0 : (dy > 10 ? 10 : dy);
      float qv;
      if (jj < 8)       qv = pe[dy * 8 + jj];
      else if (jj < 16) qv = pe[88  + tt[1] * 8  + (jj - 8)];
      else if (jj < 28) qv = pe[192 + tt[2] * 12 + (jj - 16)];
      else              qv = pe[576 + tt[3] * 8  + (jj - 28)];
      v = te + qv;
    }
    xs[(SEQ - 1) * LDX + tid] = v;
  }
  __syncthreads();

  // per-thread tile indices (clamped variants for safe dead-lane loads)
  int colv[5], colvc[5];
  #pragma unroll
  for (int v = 0; v < 5; ++v) { colv[v] = tx + 16 * v; colvc[v] = colv[v] < DM ? colv[v] : DM - 1; }
  int rowu[7], rowuc[7];
  #pragma unroll
  for (int u = 0; u < 7; ++u) { rowu[u] = ty + 16 * u; rowuc[u] = rowu[u] < SEQ ? rowu[u] : SEQ - 1; }
  int cu5[5];
  #pragma unroll
  for (int u = 0; u < 5; ++u) { int c = ty + 16 * u; cu5[u] = c < DM ? c : DM - 1; }

  // ---- 2 resblocks ----
  for (int r = 0; r < 2; ++r) {
    const float* tw1T = p.ws + OFF_TW1T + r * SZ_TW1T;
    const float* tw2T = p.ws + OFF_TW2T + r * SZ_TW2T;
    const float* cw1T = p.ws + OFF_CW1T + r * SZ_CWT;
    const float* cw2T = p.ws + OFF_CW2T + r * SZ_CWT;
    const float* tb1 = p.tb1[r]; const float* tb2 = p.tb2[r];
    const float* cb1 = p.cb1[r]; const float* cb2 = p.cb2[r];

    // transpose xs -> yb as xT[c][t]
    for (int i = tid; i < DM * SEQ; i += 256) {
      int c = i / SEQ, t = i - c * SEQ;
      yb[c * LDT + t] = xs[t * LDX + c];
    }
    __syncthreads();

    // A: y1[c][j] = relu(tb1[j] + sum_t x[t][c]*tw1[t][j]);  K contiguous via xT/tw1T
    {
      float acc[5][5] = {};
      for (int t = 0; t < TLEN; t += 4) {
        float a[5][4], w[5][4];
        #pragma unroll
        for (int u = 0; u < 5; ++u) {
          float4 v4 = *(const float4*)&yb[cu5[u] * LDT + t];
          a[u][0] = v4.x; a[u][1] = v4.y; a[u][2] = v4.z; a[u][3] = v4.w;
        }
        #pragma unroll
        for (int v = 0; v < 5; ++v) {
          float4 v4 = LD4G(&tw1T[colvc[v] * LDWT + t]);
          w[v][0] = v4.x; w[v][1] = v4.y; w[v][2] = v4.z; w[v][3] = v4.w;
        }
        #pragma unroll
        for (int k = 0; k < 4; ++k)
          #pragma unroll
          for (int u = 0; u < 5; ++u)
            #pragma unroll
            for (int v = 0; v < 5; ++v) acc[u][v] = fmaf(a[u][k], w[v][k], acc[u][v]);
      }
      { // tail t = 100
        float a[5], w[5];
        #pragma unroll
        for (int u = 0; u < 5; ++u) a[u] = yb[cu5[u] * LDT + TLEN];
        #pragma unroll
        for (int v = 0; v < 5; ++v) w[v] = tw1T[colvc[v] * LDWT + TLEN];
        #pragma unroll
        for (int u = 0; u < 5; ++u)
          #pragma unroll
          for (int v = 0; v < 5; ++v) acc[u][v] = fmaf(a[u], w[v], acc[u][v]);
      }
      __syncthreads();  // all xT reads done before overwriting yb with y1
      #pragma unroll
      for (int u = 0; u < 5; ++u) {
        int c = ty + 16 * u;
        if (c < DM) {
          #pragma unroll
          for (int v = 0; v < 5; ++v)
            if (colv[v] < DM) yb[c * LDY + colv[v]] = fmaxf(acc[u][v] + tb1[colv[v]], 0.f);
        }
      }
    }
    __syncthreads();

    // B: x[t][c] += tb2[t] + sum_j y1[c][j]*tw2[j][t]
    {
      float acc[7][5] = {};
      for (int j = 0; j < DM; j += 4) {
        float a[5][4], w[7][4];
        #pragma unroll
        for (int v = 0; v < 5; ++v) {
          float4 v4 = *(const float4*)&yb[colvc[v] * LDY + j];
          a[v][0] = v4.x; a[v][1] = v4.y; a[v][2] = v4.z; a[v][3] = v4.w;
        }
        #pragma unroll
        for (int u = 0; u < 7; ++u) {
          float4 v4 = LD4G(&tw2T[rowuc[u] * DM + j]);
          w[u][0] = v4.x; w[u][1] = v4.y; w[u][2] = v4.z; w[u][3] = v4.w;
        }
        #pragma unroll
        for (int k = 0; k < 4; ++k)
          #pragma unroll
          for (int u = 0; u < 7; ++u)
            #pragma unroll
            for (int v = 0; v < 5; ++v) acc[u][v] = fmaf(a[v][k], w[u][k], acc[u][v]);
      }
      #pragma unroll
      for (int u = 0; u < 7; ++u) {
        int t = rowu[u];
        if (t < SEQ) {
          float tb2t = tb2[t];
          #pragma unroll
          for (int v = 0; v < 5; ++v)
            if (colv[v] < DM) xs[t * LDX + colv[v]] += acc[u][v] + tb2t;
        }
      }
    }
    __syncthreads();

    // C: y2[t][j] = relu(cb1[j] + sum_c x[t][c]*cw1[c][j])
    {
      float acc[7][5] = {};
      for (int c = 0; c < DM; c += 4) {
        float a[7][4], w[5][4];
        #pragma unroll
        for (int u = 0; u < 7; ++u) {
          float4 v4 = *(const float4*)&xs[rowuc[u] * LDX + c];
          a[u][0] = v4.x; a[u][1] = v4.y; a[u][2] = v4.z; a[u][3] = v4.w;
        }
        #pragma unroll
        for (int v = 0; v < 5; ++v) {
          float4 v4 = LD4G(&cw1T[colvc[v] * DM + c]);
          w[v][0] = v4.x; w[v][1] = v4.y; w[v][2] = v4.z; w[v][3] = v4.w;
        }
        #pragma unroll
        for (int k = 0; k < 4; ++k)
          #pragma unroll
          for (int u = 0; u < 7; ++u)
            #pragma unroll
            for (int v = 0; v < 5; ++v) acc[u][v] = fmaf(a[u][k], w[v][k], acc[u][v]);
      }
      __syncthreads();  // all y1 reads done (from B) & xs reads done before writing y2
      #pragma unroll
      for (int u = 0; u < 7; ++u) {
        int t = rowu[u];
        if (t < SEQ) {
          #pragma unroll
          for (int v = 0; v < 5; ++v)
            if (colv[v] < DM) yb[t * LDY + colv[v]] = fmaxf(acc[u][v] + cb1[colv[v]], 0.f);
        }
      }
    }
    __syncthreads();

    // D: x[t][c] += cb2[c] + sum_j y2[t][j]*cw2[j][c]
    {
      float acc[7][5] = {};
      for (int j = 0; j < DM; j += 4) {
        float a[7][4], w[5][4];
        #pragma unroll
        for (int u = 0; u < 7; ++u) {
          float4 v4 = *(const float4*)&yb[rowuc[u] * LDY + j];
          a[u][0] = v4.x; a[u][1] = v4.y; a[u][2] = v4.z; a[u][3] = v4.w;
        }
        #pragma unroll
        for (int v = 0; v < 5; ++v) {
          float4 v4 = LD4G(&cw2T[colvc[v] * DM + j]);
          w[v][0] = v4.x; w[v][1] = v4.y; w[v][2] = v4.z; w[v][3] = v4.w;
        }
        #pragma unroll
        for (int k = 0; k < 4; ++k)
          #pragma unroll
          for (int u = 0; u < 7; ++u)
            #pragma unroll
            for (int v = 0; v < 5; ++v) acc[u][v] = fmaf(a[u][k], w[v][k], acc[u][v]);
      }
      #pragma unroll
      for (int u = 0; u < 7; ++u) {
        int t = rowu[u];
        if (t < SEQ) {
          #pragma unroll
          for (int v = 0; v < 5; ++v)
            if (colv[v] < DM) xs[t * LDX + colv[v]] += acc[u][v] + cb2[colv[v]];
        }
      }
    }
    __syncthreads();
  }

  // ---- head ----
  if (tid < DM) {
    float acc = 0.f;
    for (int t = 0; t < SEQ; ++t) acc = fmaf(xs[t * LDX + tid], p.wp_time[t], acc);
    red[tid] = (acc + p.bp_time[0]) * p.w_head[tid];
  }
  __syncthreads();
  if (tid == 0) {
    float yv = 0.f;
    #pragma unroll 8
    for (int i = 0; i < DM; ++i) yv += red[i];
    yv = fmaxf(yv + p.b_head[0], 0.f);
    p.out[b]      = yv * s + hist_mean;
    p.out[NB + b] = s;
  }
}

extern "C" void kernel_launch(void* const* d_in, const int* in_sizes, int n_in,
                              void* d_out, int out_size, void* d_ws, size_t ws_size,
                              hipStream_t stream) {
  (void)in_sizes; (void)n_in; (void)out_size; (void)ws_size;

  SetupParams sp;
  sp.tw1[0] = (const float*)d_in[9];  sp.tw2[0] = (const float*)d_in[11];
  sp.cw1[0] = (const float*)d_in[13]; sp.cw2[0] = (const float*)d_in[15];
  sp.tw1[1] = (const float*)d_in[17]; sp.tw2[1] = (const float*)d_in[19];
  sp.cw1[1] = (const float*)d_in[21]; sp.cw2[1] = (const float*)d_in[23];
  sp.ws = (float*)d_ws;
  hipLaunchKernelGGL(setup_kernel, dim3(32), dim3(256), 0, stream, sp);

  Params p;
  p.history   = (const float*)d_in[0];
  p.ts        = (const int*)  d_in[1];
  p.target_ts = (const int*)  d_in[2];
  p.task      = (const int*)  d_in[3];
  p.w_np = (const float*)d_in[4];  p.b_np = (const float*)d_in[5];
  p.w_wp = (const float*)d_in[6];  p.b_wp = (const float*)d_in[7];
  p.task_emb = (const float*)d_in[8];
  p.tb1[0] = (const float*)d_in[10]; p.tb2[0] = (const float*)d_in[12];
  p.cb1[0] = (const float*)d_in[14]; p.cb2[0] = (const float*)d_in[16];
  p.tb1[1] = (const float*)d_in[18]; p.tb2[1] = (const float*)d_in[20];
  p.cb1[1] = (const float*)d_in[22]; p.cb2[1] = (const float*)d_in[24];
  p.wp_time = (const float*)d_in[25]; p.bp_time = (const float*)d_in[26];
  p.w_head  = (const float*)d_in[27]; p.b_head  = (const float*)d_in[28];
  p.ws  = (const float*)d_ws;
  p.out = (float*)d_out;
  hipLaunchKernelGGL(fpfn_kernel, dim3(NB), dim3(256), 0, stream, p);
}

// Round 3
// 1125.720 us; speedup vs baseline: 1.6893x; 1.5817x over previous
//
#include <hip/hip_runtime.h>
#include <math.h>

#define NB   8192
#define TLEN 100
#define SEQ  101
#define DE   36
#define DM   72
#define OPLD 104   // operand buffer row stride (ushorts); mult of 8 -> 16B-aligned b128
#define XLD  73    // x_f32 row stride (odd -> conflict-free column access)

// frag sets per resblock: A:4k*5n=20, B:3*7=21, C:3*5=15, D:3*5=15 -> 71
#define RB_SETS    71
#define TOTAL_SETS 142
#define LO_V4      (TOTAL_SETS * 64)   // uint4 offset of lo-frag array in ws

typedef __attribute__((ext_vector_type(8))) short short8v;
typedef __attribute__((ext_vector_type(4))) float f32x4;
union U16 { uint4 u; short8v s; };

#define MFMA16(a, b, c) __builtin_amdgcn_mfma_f32_16x16x32_bf16((a), (b), (c), 0, 0, 0)

static __device__ __forceinline__ unsigned short f2bf(float f) {
  unsigned u = __float_as_uint(f);
  unsigned r = ((u >> 16) & 1u) + 0x7fffu;   // round-to-nearest-even
  u += r;
  return (unsigned short)(u >> 16);
}
static __device__ __forceinline__ float bf2f(unsigned short h) {
  return __uint_as_float(((unsigned)h) << 16);
}

struct SetupParams {
  const float* tw1[2]; const float* tw2[2]; const float* cw1[2]; const float* cw2[2];
  unsigned* ws;
};

// Pack weights into MFMA B-fragment order (hi and lo bf16 halves), zero-padded
// for k >= K and n >= N.  Frag slot bijection: k = kstep*32 + (lane>>4)*8 + e,
// n = ntile*16 + (lane&15); dword r holds elements e=2r (lo16) and e=2r+1 (hi16).
__global__ void setup_kernel(SetupParams sp) {
  int s = blockIdx.x;           // set id 0..141
  int tid = threadIdx.x;        // 256
  int l = tid >> 2, r = tid & 3;
  int rb = s / RB_SETS, s2 = s % RB_SETS;
  const float* W; int K, N, ks, nt;
  if (s2 < 20)      { ks = s2 / 5;        nt = s2 % 5;        W = sp.tw1[rb]; K = SEQ; N = DM; }
  else if (s2 < 41) { int t = s2 - 20; ks = t / 7; nt = t % 7; W = sp.tw2[rb]; K = DM;  N = SEQ; }
  else if (s2 < 56) { int t = s2 - 41; ks = t / 5; nt = t % 5; W = sp.cw1[rb]; K = DM;  N = DM; }
  else              { int t = s2 - 56; ks = t / 5; nt = t % 5; W = sp.cw2[rb]; K = DM;  N = DM; }
  int g = l >> 4;
  int n = nt * 16 + (l & 15);
  int k0 = ks * 32 + g * 8 + 2 * r;
  int k1 = k0 + 1;
  float f0 = (k0 < K && n < N) ? W[k0 * N + n] : 0.f;
  float f1 = (k1 < K && n < N) ? W[k1 * N + n] : 0.f;
  unsigned short h0 = f2bf(f0), h1 = f2bf(f1);
  unsigned short l0 = f2bf(f0 - bf2f(h0)), l1 = f2bf(f1 - bf2f(h1));
  unsigned idx = (unsigned)s * 256u + (unsigned)l * 4u + (unsigned)r;
  sp.ws[idx] = (unsigned)h0 | ((unsigned)h1 << 16);
  sp.ws[(unsigned)TOTAL_SETS * 256u + idx] = (unsigned)l0 | ((unsigned)l1 << 16);
}

struct Params {
  const float *history; const int *ts; const int *target_ts; const int *task;
  const float *w_np; const float *b_np; const float *w_wp; const float *b_wp;
  const float *task_emb;
  const float *tb1[2]; const float *tb2[2]; const float *cb1[2]; const float *cb2[2];
  const float *wp_time; const float *bp_time; const float *w_head; const float *b_head;
  const uint4 *wf; float *out;
};

// GEMM phase: each wave owns tiles wave, wave+4, ... of an MTxNT grid.
// acc[i] = sum over ksteps of (Ahi*Bhi + Ahi*Blo + Alo*Bhi).
template<int NTN, int NTILES, int KSTEPS, int MAXT>
static __device__ __forceinline__ void mfma_phase(
    const unsigned short* __restrict__ opb_hi, const unsigned short* __restrict__ opb_lo,
    const uint4* __restrict__ wf, int set_base, int lane, int wave, f32x4* acc) {
  const int g8 = (lane >> 4) * 8;
  const int m16 = lane & 15;
  #pragma unroll
  for (int i = 0; i < MAXT; ++i) {
    int tile = wave + i * 4;
    if (tile < NTILES) {
      int mt = tile / NTN, nt = tile % NTN;
      int abase = (mt * 16 + m16) * OPLD + g8;
      f32x4 a = {0.f, 0.f, 0.f, 0.f};
      #pragma unroll
      for (int ks = 0; ks < KSTEPS; ++ks) {
        short8v ah = *(const short8v*)&opb_hi[abase + ks * 32];
        short8v al = *(const short8v*)&opb_lo[abase + ks * 32];
        int set = set_base + ks * NTN + nt;
        U16 uh; uh.u = wf[(size_t)set * 64 + lane];
        U16 ul; ul.u = wf[(size_t)(LO_V4) + (size_t)set * 64 + lane];
        a = MFMA16(ah, uh.s, a);
        a = MFMA16(ah, ul.s, a);
        a = MFMA16(al, uh.s, a);
      }
      acc[i] = a;
    }
  }
}

__global__ __launch_bounds__(256, 2) void fpfn_kernel(Params p) {
  __shared__ __align__(16) unsigned short opb_hi[112 * OPLD];
  __shared__ __align__(16) unsigned short opb_lo[112 * OPLD];
  __shared__ __align__(16) float x_f32[SEQ * XLD];
  __shared__ float pe[640];
  __shared__ float sh[TLEN];
  __shared__ unsigned short datesu[TLEN * 4];
  __shared__ float part[4];

  const int tid  = threadIdx.x;
  const int b    = blockIdx.x;
  const int lane = tid & 63;
  const int wave = tid >> 6;

  // ---- zero operand buffers (finite everywhere that may be read) ----
  {
    uint4 z = {0, 0, 0, 0};
    uint4* zh = (uint4*)opb_hi;
    uint4* zl = (uint4*)opb_lo;
    for (int i = tid; i < 112 * OPLD * 2 / 16; i += 256) { zh[i] = z; zl[i] = z; }
  }

  // ---- positional tables ----
  for (int idx = tid; idx < 640; idx += 256) {
    int periods, freqs, row, col;
    if (idx < 88)       { periods = 10; freqs = 4; row = idx >> 3;        col = idx & 7; }
    else if (idx < 192) { periods = 12; freqs = 4; row = (idx - 88) >> 3; col = (idx - 88) & 7; }
    else if (idx < 576) { periods = 31; freqs = 6; int r2 = idx - 192; row = r2 / 12; col = r2 - row * 12; }
    else                { periods = 7;  freqs = 4; row = (idx - 576) >> 3; col = (idx - 576) & 7; }
    int jf = (col < freqs) ? col : (col - freqs);
    float pip = (float)(3.14159265358979323846 / (double)periods);
    float ang = pip * (float)(1 << jf) * ((float)row - 1.0f);
    pe[idx] = (col < freqs) ? sinf(ang) : cosf(ang);
  }

  auto blockReduce = [&](float v) -> float {
    #pragma unroll
    for (int o = 32; o > 0; o >>= 1) v += __shfl_xor(v, o, 64);
    __syncthreads();
    if (lane == 0) part[wave] = v;
    __syncthreads();
    return part[0] + part[1] + part[2] + part[3];
  };

  // ---- robust_scale (exact fp32 reference semantics) ----
  float h  = (tid < TLEN) ? p.history[(size_t)b * TLEN + tid] : 0.f;
  float nz = (tid < TLEN && h != 0.f) ? 1.f : 0.f;
  float cnt  = blockReduce(nz);
  float hsum = blockReduce(h);
  float safe = fmaxf(cnt, 1.f);
  float mean = hsum / safe;
  float var  = blockReduce(nz * (h - mean) * (h - mean)) / safe;
  float mean_z = (cnt > 0.f) ? mean : 0.f;
  float std_z  = (cnt > 0.f) ? sqrtf(var) : 0.f;
  float upper  = mean_z + 2.f * std_z;
  float clipped = fminf(fmaxf(h, 0.f), upper);
  float nz2  = (tid < TLEN && clipped != 0.f) ? 1.f : 0.f;
  float cnt2 = blockReduce(nz2);
  float csum = blockReduce(nz2 * clipped);
  float safe2 = fmaxf(cnt2, 1.f);
  float mc = csum / safe2;
  float vc = blockReduce(nz2 * (clipped - mc) * (clipped - mc)) / safe2;
  float mc_z = (cnt2 > 0.f) ? mc : 0.f;
  float sc_z = (cnt2 > 0.f) ? sqrtf(vc) : 0.f;
  float s = mc_z + sc_z + 1e-4f;
  float hist_mean = hsum * (1.f / (float)TLEN);

  int yr99 = p.ts[((size_t)b * TLEN + (TLEN - 1)) * 4 + 0];
  if (tid < TLEN) {
    sh[tid] = fminf(fmaxf(h / s, 0.f), 3.f);
    const int* tsb = p.ts + ((size_t)b * TLEN + tid) * 4;
    int dy = yr99 - tsb[0]; dy = dy < 0 ? 0 : (dy > 10 ? 10 : dy);
    datesu[tid * 4 + 0] = (unsigned short)(dy * 8);
    datesu[tid * 4 + 1] = (unsigned short)(88  + tsb[1] * 8);
    datesu[tid * 4 + 2] = (unsigned short)(192 + tsb[2] * 12);
    datesu[tid * 4 + 3] = (unsigned short)(576 + tsb[3] * 8);
  }
  __syncthreads();

  // ---- build x: f32 into x_f32[t][c], bf16 hi/lo transposed into opb[c][t] ----
  for (int idx = tid; idx < TLEN * DM; idx += 256) {
    int t = idx / DM;
    int j = idx - t * DM;
    float sv = sh[t];
    float v;
    if (j < DE) {
      v = fmaxf(fmaf(sv, p.w_np[j], p.b_np[j]), 0.f);
    } else {
      int jj = j - DE;
      float e1 = fmaxf(fmaf(sv, p.w_wp[jj], p.b_wp[jj]), 0.f);
      float pv;
      if (jj < 8)       pv = pe[datesu[t * 4 + 0] + jj];
      else if (jj < 16) pv = pe[datesu[t * 4 + 1] + (jj - 8)];
      else if (jj < 28) pv = pe[datesu[t * 4 + 2] + (jj - 16)];
      else              pv = pe[datesu[t * 4 + 3] + (jj - 28)];
      v = e1 + pv;
    }
    x_f32[t * XLD + j] = v;
    unsigned short hb = f2bf(v);
    opb_hi[j * OPLD + t] = hb;
    opb_lo[j * OPLD + t] = f2bf(v - bf2f(hb));
  }
  if (tid < DM) {  // target row t=100
    int tk = p.task[b];
    float te = p.task_emb[tk * DE + (tid < DE ? tid : tid - DE)];
    float v = te;
    if (tid >= DE) {
      int jj = tid - DE;
      const int* tt = p.target_ts + (size_t)b * 5;
      int dy = yr99 - tt[0]; dy = dy < 0 ? 0 : (dy > 10 ? 10 : dy);
      float qv;
      if (jj < 8)       qv = pe[dy * 8 + jj];
      else if (jj < 16) qv = pe[88  + tt[1] * 8  + (jj - 8)];
      else if (jj < 28) qv = pe[192 + tt[2] * 12 + (jj - 16)];
      else              qv = pe[576 + tt[3] * 8  + (jj - 28)];
      v = te + qv;
    }
    x_f32[(SEQ - 1) * XLD + tid] = v;
    unsigned short hb = f2bf(v);
    opb_hi[tid * OPLD + (SEQ - 1)] = hb;
    opb_lo[tid * OPLD + (SEQ - 1)] = f2bf(v - bf2f(hb));
  }
  __syncthreads();

  const int m16 = lane & 15;
  const int rowb = (lane >> 4) * 4;
  f32x4 acc[9];

  for (int rb = 0; rb < 2; ++rb) {
    const int base = rb * RB_SETS;
    const float* tb1 = p.tb1[rb]; const float* tb2 = p.tb2[rb];
    const float* cb1 = p.cb1[rb]; const float* cb2 = p.cb2[rb];

    // ---- A: y1[c][j] = relu(tb1[j] + sum_t xT[c][t] tw1[t][j]);  M=c(5) N=j(5) K=101(4) ----
    mfma_phase<5, 25, 4, 7>(opb_hi, opb_lo, p.wf, base + 0, lane, wave, acc);
    __syncthreads();
    #pragma unroll
    for (int i = 0; i < 7; ++i) {
      int tile = wave + i * 4;
      if (tile < 25) {
        int mt = tile / 5, nt = tile % 5;
        int j = nt * 16 + m16;
        float bias = (j < DM) ? tb1[j] : 0.f;
        #pragma unroll
        for (int rg = 0; rg < 4; ++rg) {
          int c = mt * 16 + rowb + rg;
          if (c < DM && j < DM) {
            float v = fmaxf(acc[i][rg] + bias, 0.f);
            unsigned short hb = f2bf(v);
            opb_hi[c * OPLD + j] = hb;
            opb_lo[c * OPLD + j] = f2bf(v - bf2f(hb));
          }
        }
      }
    }
    __syncthreads();

    // ---- B: x[t][c] += tb2[t] + sum_j y1[c][j] tw2[j][t];  M=c(5) N=t(7) K=72(3) ----
    mfma_phase<7, 35, 3, 9>(opb_hi, opb_lo, p.wf, base + 20, lane, wave, acc);
    __syncthreads();
    #pragma unroll
    for (int i = 0; i < 9; ++i) {
      int tile = wave + i * 4;
      if (tile < 35) {
        int mt = tile / 7, nt = tile % 7;
        int t = nt * 16 + m16;
        float bias = (t < SEQ) ? tb2[t] : 0.f;
        #pragma unroll
        for (int rg = 0; rg < 4; ++rg) {
          int c = mt * 16 + rowb + rg;
          if (c < DM && t < SEQ) {
            float xn = x_f32[t * XLD + c] + acc[i][rg] + bias;
            x_f32[t * XLD + c] = xn;
            unsigned short hb = f2bf(xn);
            opb_hi[t * OPLD + c] = hb;
            opb_lo[t * OPLD + c] = f2bf(xn - bf2f(hb));
          }
        }
      }
    }
    __syncthreads();

    // ---- C: y2[t][j] = relu(cb1[j] + sum_c x[t][c] cw1[c][j]);  M=t(7) N=j(5) K=72(3) ----
    mfma_phase<5, 35, 3, 9>(opb_hi, opb_lo, p.wf, base + 41, lane, wave, acc);
    __syncthreads();
    #pragma unroll
    for (int i = 0; i < 9; ++i) {
      int tile = wave + i * 4;
      if (tile < 35) {
        int mt = tile / 5, nt = tile % 5;
        int j = nt * 16 + m16;
        float bias = (j < DM) ? cb1[j] : 0.f;
        #pragma unroll
        for (int rg = 0; rg < 4; ++rg) {
          int t = mt * 16 + rowb + rg;
          if (t < SEQ && j < DM) {
            float v = fmaxf(acc[i][rg] + bias, 0.f);
            unsigned short hb = f2bf(v);
            opb_hi[t * OPLD + j] = hb;
            opb_lo[t * OPLD + j] = f2bf(v - bf2f(hb));
          }
        }
      }
    }
    __syncthreads();

    // ---- D: x[t][c] += cb2[c] + sum_j y2[t][j] cw2[j][c];  M=t(7) N=c(5) K=72(3) ----
    mfma_phase<5, 35, 3, 9>(opb_hi, opb_lo, p.wf, base + 56, lane, wave, acc);
    __syncthreads();
    #pragma unroll
    for (int i = 0; i < 9; ++i) {
      int tile = wave + i * 4;
      if (tile < 35) {
        int mt = tile / 5, nt = tile % 5;
        int c = nt * 16 + m16;
        float bias = (c < DM) ? cb2[c] : 0.f;
        #pragma unroll
        for (int rg = 0; rg < 4; ++rg) {
          int t = mt * 16 + rowb + rg;
          if (t < SEQ && c < DM) {
            float xn = x_f32[t * XLD + c] + acc[i][rg] + bias;
            x_f32[t * XLD + c] = xn;
            unsigned short hb = f2bf(xn);   // xT for next resblock's A-step
            opb_hi[c * OPLD + t] = hb;
            opb_lo[c * OPLD + t] = f2bf(xn - bf2f(hb));
          }
        }
      }
    }
    __syncthreads();
  }

  // ---- head (fp32 exact) ----
  if (tid < DM) {
    float a = 0.f;
    for (int t = 0; t < SEQ; ++t) a = fmaf(x_f32[t * XLD + tid], p.wp_time[t], a);
    sh[tid] = (a + p.bp_time[0]) * p.w_head[tid];
  }
  __syncthreads();
  if (tid == 0) {
    float yv = 0.f;
    #pragma unroll 8
    for (int i = 0; i < DM; ++i) yv += sh[i];
    yv = fmaxf(yv + p.b_head[0], 0.f);
    p.out[b]      = yv * s + hist_mean;
    p.out[NB + b] = s;
  }
}

extern "C" void kernel_launch(void* const* d_in, const int* in_sizes, int n_in,
                              void* d_out, int out_size, void* d_ws, size_t ws_size,
                              hipStream_t stream) {
  (void)in_sizes; (void)n_in; (void)out_size; (void)ws_size;

  SetupParams sp;
  sp.tw1[0] = (const float*)d_in[9];  sp.tw2[0] = (const float*)d_in[11];
  sp.cw1[0] = (const float*)d_in[13]; sp.cw2[0] = (const float*)d_in[15];
  sp.tw1[1] = (const float*)d_in[17]; sp.tw2[1] = (const float*)d_in[19];
  sp.cw1[1] = (const float*)d_in[21]; sp.cw2[1] = (const float*)d_in[23];
  sp.ws = (unsigned*)d_ws;
  hipLaunchKernelGGL(setup_kernel, dim3(TOTAL_SETS), dim3(256), 0, stream, sp);

  Params p;
  p.history   = (const float*)d_in[0];
  p.ts        = (const int*)  d_in[1];
  p.target_ts = (const int*)  d_in[2];
  p.task      = (const int*)  d_in[3];
  p.w_np = (const float*)d_in[4];  p.b_np = (const float*)d_in[5];
  p.w_wp = (const float*)d_in[6];  p.b_wp = (const float*)d_in[7];
  p.task_emb = (const float*)d_in[8];
  p.tb1[0] = (const float*)d_in[10]; p.tb2[0] = (const float*)d_in[12];
  p.cb1[0] = (const float*)d_in[14]; p.cb2[0] = (const float*)d_in[16];
  p.tb1[1] = (const float*)d_in[18]; p.tb2[1] = (const float*)d_in[20];
  p.cb1[1] = (const float*)d_in[22]; p.cb2[1] = (const float*)d_in[24];
  p.wp_time = (const float*)d_in[25]; p.bp_time = (const float*)d_in[26];
  p.w_head  = (const float*)d_in[27]; p.b_head  = (const float*)d_in[28];
  p.wf  = (const uint4*)d_ws;
  p.out = (float*)d_out;
  hipLaunchKernelGGL(fpfn_kernel, dim3(NB), dim3(256), 0, stream, p);
}

// Round 4
// 908.875 us; speedup vs baseline: 2.0924x; 1.2386x over previous
//
#include <hip/hip_runtime.h>
#include <math.h>

#define NB   8192
#define TLEN 100
#define SEQ  101
#define DE   36
#define DM   72
#define OPLD 104    // operand buffer row stride (fp16 elems); mult of 8 -> 16B-aligned b128
#define OPN  10496  // opb element count (max read index 10495 with clamped rows)
#define XLD  73     // x_f32 row stride (odd -> conflict-free column access)

// frag sets per resblock: A:4k*5n=20, B:3*7=21, C:3*5=15, D:3*5=15 -> 71
#define RB_SETS    71
#define TOTAL_SETS 142
#define LO_V4      (TOTAL_SETS * 64)   // uint4 offset of lo-frag array in ws

typedef _Float16 half8v __attribute__((ext_vector_type(8)));
typedef __attribute__((ext_vector_type(4))) float f32x4;
union U16 { uint4 u; half8v h; };

#define MFMAH(a, b, c) __builtin_amdgcn_mfma_f32_16x16x32_f16((a), (b), (c), 0, 0, 0)

static __device__ __forceinline__ unsigned short f2h(float f) {
  union { _Float16 h; unsigned short u; } c;
  c.h = (_Float16)f;
  return c.u;
}

struct SetupParams {
  const float* tw1[2]; const float* tw2[2]; const float* cw1[2]; const float* cw2[2];
  unsigned* ws;
};

// Pack weights into MFMA B-fragment order as fp16 hi + fp16 lo (residual),
// zero-padded for k >= K and n >= N.  Slot bijection: k = kstep*32 + (lane>>4)*8 + e,
// n = ntile*16 + (lane&15); dword r holds elements e=2r (lo16) and e=2r+1 (hi16).
__global__ void setup_kernel(SetupParams sp) {
  int s = blockIdx.x;           // set id 0..141
  int tid = threadIdx.x;        // 256
  int l = tid >> 2, r = tid & 3;
  int rb = s / RB_SETS, s2 = s % RB_SETS;
  const float* W; int K, N, ks, nt;
  if (s2 < 20)      { ks = s2 / 5;        nt = s2 % 5;        W = sp.tw1[rb]; K = SEQ; N = DM; }
  else if (s2 < 41) { int t = s2 - 20; ks = t / 7; nt = t % 7; W = sp.tw2[rb]; K = DM;  N = SEQ; }
  else if (s2 < 56) { int t = s2 - 41; ks = t / 5; nt = t % 5; W = sp.cw1[rb]; K = DM;  N = DM; }
  else              { int t = s2 - 56; ks = t / 5; nt = t % 5; W = sp.cw2[rb]; K = DM;  N = DM; }
  int g = l >> 4;
  int n = nt * 16 + (l & 15);
  int k0 = ks * 32 + g * 8 + 2 * r;
  int k1 = k0 + 1;
  float f0 = (k0 < K && n < N) ? W[k0 * N + n] : 0.f;
  float f1 = (k1 < K && n < N) ? W[k1 * N + n] : 0.f;
  union { _Float16 h; unsigned short u; } h0, h1;
  h0.h = (_Float16)f0; h1.h = (_Float16)f1;
  unsigned short l0 = f2h(f0 - (float)h0.h), l1 = f2h(f1 - (float)h1.h);
  unsigned idx = (unsigned)s * 256u + (unsigned)l * 4u + (unsigned)r;
  sp.ws[idx] = (unsigned)h0.u | ((unsigned)h1.u << 16);
  sp.ws[(unsigned)TOTAL_SETS * 256u + idx] = (unsigned)l0 | ((unsigned)l1 << 16);
}

struct Params {
  const float *history; const int *ts; const int *target_ts; const int *task;
  const float *w_np; const float *b_np; const float *w_wp; const float *b_wp;
  const float *task_emb;
  const float *tb1[2]; const float *tb2[2]; const float *cb1[2]; const float *cb2[2];
  const float *wp_time; const float *bp_time; const float *w_head; const float *b_head;
  const uint4 *wf; float *out;
};

// GEMM phase: each wave owns tiles wave, wave+4, ...  acc = sum_ks (Ah*Wh + Ah*Wl).
template<int NTN, int NTILES, int KSTEPS, int MAXT>
static __device__ __forceinline__ void mfma_phase(
    const unsigned short* __restrict__ opb,
    const uint4* __restrict__ wf, int set_base, int lane, int wave, f32x4* acc) {
  const int g8 = (lane >> 4) * 8;
  const int m16 = lane & 15;
  #pragma unroll
  for (int i = 0; i < MAXT; ++i) {
    int tile = wave + i * 4;
    if (tile < NTILES) {
      int mt = tile / NTN, nt = tile % NTN;
      int mrow = mt * 16 + m16; mrow = mrow < SEQ ? mrow : SEQ - 1;  // keep reads in-bounds
      int abase = mrow * OPLD + g8;
      f32x4 a = {0.f, 0.f, 0.f, 0.f};
      #pragma unroll
      for (int ks = 0; ks < KSTEPS; ++ks) {
        half8v ah = *(const half8v*)&opb[abase + ks * 32];
        int set = set_base + ks * NTN + nt;
        U16 uh; uh.u = wf[(size_t)set * 64 + lane];
        U16 ul; ul.u = wf[(size_t)LO_V4 + (size_t)set * 64 + lane];
        a = MFMAH(ah, uh.h, a);
        a = MFMAH(ah, ul.h, a);
      }
      acc[i] = a;
    }
  }
}

__global__ __launch_bounds__(256, 3) void fpfn_kernel(Params p) {
  __shared__ __align__(16) unsigned short opb[OPN];     // time-shared fp16 operand buffer
  __shared__ __align__(16) float x_f32[SEQ * XLD];      // fp32 residual stream
  __shared__ float pe[640];
  __shared__ float sh[TLEN];
  __shared__ unsigned short datesu[TLEN * 4];
  __shared__ float part[4];

  const int tid  = threadIdx.x;
  const int b    = blockIdx.x;
  const int lane = tid & 63;
  const int wave = tid >> 6;

  // ---- zero operand buffer (pad regions must stay finite/zero) ----
  {
    uint4 z = {0, 0, 0, 0};
    uint4* zp = (uint4*)opb;
    for (int i = tid; i < OPN / 8; i += 256) zp[i] = z;
  }

  // ---- positional tables ----
  for (int idx = tid; idx < 640; idx += 256) {
    int periods, freqs, row, col;
    if (idx < 88)       { periods = 10; freqs = 4; row = idx >> 3;        col = idx & 7; }
    else if (idx < 192) { periods = 12; freqs = 4; row = (idx - 88) >> 3; col = (idx - 88) & 7; }
    else if (idx < 576) { periods = 31; freqs = 6; int r2 = idx - 192; row = r2 / 12; col = r2 - row * 12; }
    else                { periods = 7;  freqs = 4; row = (idx - 576) >> 3; col = (idx - 576) & 7; }
    int jf = (col < freqs) ? col : (col - freqs);
    float pip = (float)(3.14159265358979323846 / (double)periods);
    float ang = pip * (float)(1 << jf) * ((float)row - 1.0f);
    pe[idx] = (col < freqs) ? sinf(ang) : cosf(ang);
  }

  auto blockReduce = [&](float v) -> float {
    #pragma unroll
    for (int o = 32; o > 0; o >>= 1) v += __shfl_xor(v, o, 64);
    __syncthreads();
    if (lane == 0) part[wave] = v;
    __syncthreads();
    return part[0] + part[1] + part[2] + part[3];
  };

  // ---- robust_scale (exact fp32 reference semantics) ----
  float h  = (tid < TLEN) ? p.history[(size_t)b * TLEN + tid] : 0.f;
  float nz = (tid < TLEN && h != 0.f) ? 1.f : 0.f;
  float cnt  = blockReduce(nz);
  float hsum = blockReduce(h);
  float safe = fmaxf(cnt, 1.f);
  float mean = hsum / safe;
  float var  = blockReduce(nz * (h - mean) * (h - mean)) / safe;
  float mean_z = (cnt > 0.f) ? mean : 0.f;
  float std_z  = (cnt > 0.f) ? sqrtf(var) : 0.f;
  float upper  = mean_z + 2.f * std_z;
  float clipped = fminf(fmaxf(h, 0.f), upper);
  float nz2  = (tid < TLEN && clipped != 0.f) ? 1.f : 0.f;
  float cnt2 = blockReduce(nz2);
  float csum = blockReduce(nz2 * clipped);
  float safe2 = fmaxf(cnt2, 1.f);
  float mc = csum / safe2;
  float vc = blockReduce(nz2 * (clipped - mc) * (clipped - mc)) / safe2;
  float mc_z = (cnt2 > 0.f) ? mc : 0.f;
  float sc_z = (cnt2 > 0.f) ? sqrtf(vc) : 0.f;
  float s = mc_z + sc_z + 1e-4f;
  float hist_mean = hsum * (1.f / (float)TLEN);

  int yr99 = p.ts[((size_t)b * TLEN + (TLEN - 1)) * 4 + 0];
  if (tid < TLEN) {
    sh[tid] = fminf(fmaxf(h / s, 0.f), 3.f);
    const int* tsb = p.ts + ((size_t)b * TLEN + tid) * 4;
    int dy = yr99 - tsb[0]; dy = dy < 0 ? 0 : (dy > 10 ? 10 : dy);
    datesu[tid * 4 + 0] = (unsigned short)(dy * 8);
    datesu[tid * 4 + 1] = (unsigned short)(88  + tsb[1] * 8);
    datesu[tid * 4 + 2] = (unsigned short)(192 + tsb[2] * 12);
    datesu[tid * 4 + 3] = (unsigned short)(576 + tsb[3] * 8);
  }
  __syncthreads();

  // ---- build x: f32 into x_f32[t][j], fp16 transposed into opb[j][t] ----
  // j-major index so opb xT-writes are conflict-free (consecutive t per lane)
  for (int idx = tid; idx < DM * TLEN; idx += 256) {
    int j = idx / TLEN;
    int t = idx - j * TLEN;
    float sv = sh[t];
    float v;
    if (j < DE) {
      v = fmaxf(fmaf(sv, p.w_np[j], p.b_np[j]), 0.f);
    } else {
      int jj = j - DE;
      float e1 = fmaxf(fmaf(sv, p.w_wp[jj], p.b_wp[jj]), 0.f);
      float pv;
      if (jj < 8)       pv = pe[datesu[t * 4 + 0] + jj];
      else if (jj < 16) pv = pe[datesu[t * 4 + 1] + (jj - 8)];
      else if (jj < 28) pv = pe[datesu[t * 4 + 2] + (jj - 16)];
      else              pv = pe[datesu[t * 4 + 3] + (jj - 28)];
      v = e1 + pv;
    }
    x_f32[t * XLD + j] = v;
    opb[j * OPLD + t] = f2h(v);
  }
  if (tid < DM) {  // target row t=100
    int tk = p.task[b];
    float te = p.task_emb[tk * DE + (tid < DE ? tid : tid - DE)];
    float v = te;
    if (tid >= DE) {
      int jj = tid - DE;
      const int* tt = p.target_ts + (size_t)b * 5;
      int dy = yr99 - tt[0]; dy = dy < 0 ? 0 : (dy > 10 ? 10 : dy);
      float qv;
      if (jj < 8)       qv = pe[dy * 8 + jj];
      else if (jj < 16) qv = pe[88  + tt[1] * 8  + (jj - 8)];
      else if (jj < 28) qv = pe[192 + tt[2] * 12 + (jj - 16)];
      else              qv = pe[576 + tt[3] * 8  + (jj - 28)];
      v = te + qv;
    }
    x_f32[(SEQ - 1) * XLD + tid] = v;
    opb[tid * OPLD + (SEQ - 1)] = f2h(v);
  }
  __syncthreads();

  const int m16 = lane & 15;
  const int rowb = (lane >> 4) * 4;
  f32x4 acc[9];

  for (int rb = 0; rb < 2; ++rb) {
    const int base = rb * RB_SETS;
    const float* tb1 = p.tb1[rb]; const float* tb2 = p.tb2[rb];
    const float* cb1 = p.cb1[rb]; const float* cb2 = p.cb2[rb];

    // ---- A: y1[c][j] = relu(tb1[j] + sum_t xT[c][t] tw1[t][j]);  M=c(5) N=j(5) K=101(4) ----
    mfma_phase<5, 25, 4, 7>(opb, p.wf, base + 0, lane, wave, acc);
    __syncthreads();
    #pragma unroll
    for (int i = 0; i < 7; ++i) {
      int tile = wave + i * 4;
      if (tile < 25) {
        int mt = tile / 5, nt = tile % 5;
        int j = nt * 16 + m16;
        float bias = (j < DM) ? tb1[j] : 0.f;
        #pragma unroll
        for (int rg = 0; rg < 4; ++rg) {
          int c = mt * 16 + rowb + rg;
          if (c < DM && j < DM)
            opb[c * OPLD + j] = f2h(fmaxf(acc[i][rg] + bias, 0.f));
        }
      }
    }
    __syncthreads();

    // ---- B: x[t][c] += tb2[t] + sum_j y1[c][j] tw2[j][t];  M=c(5) N=t(7) K=72(3) ----
    mfma_phase<7, 35, 3, 9>(opb, p.wf, base + 20, lane, wave, acc);
    __syncthreads();
    #pragma unroll
    for (int i = 0; i < 9; ++i) {
      int tile = wave + i * 4;
      if (tile < 35) {
        int mt = tile / 7, nt = tile % 7;
        int t = nt * 16 + m16;
        float bias = (t < SEQ) ? tb2[t] : 0.f;
        #pragma unroll
        for (int rg = 0; rg < 4; ++rg) {
          int c = mt * 16 + rowb + rg;
          if (c < DM && t < SEQ) {
            float xn = x_f32[t * XLD + c] + acc[i][rg] + bias;
            x_f32[t * XLD + c] = xn;
            opb[t * OPLD + c] = f2h(xn);
          }
        }
      }
    }
    __syncthreads();

    // ---- C: y2[t][j] = relu(cb1[j] + sum_c x[t][c] cw1[c][j]);  M=t(7) N=j(5) K=72(3) ----
    mfma_phase<5, 35, 3, 9>(opb, p.wf, base + 41, lane, wave, acc);
    __syncthreads();
    #pragma unroll
    for (int i = 0; i < 9; ++i) {
      int tile = wave + i * 4;
      if (tile < 35) {
        int mt = tile / 5, nt = tile % 5;
        int j = nt * 16 + m16;
        float bias = (j < DM) ? cb1[j] : 0.f;
        #pragma unroll
        for (int rg = 0; rg < 4; ++rg) {
          int t = mt * 16 + rowb + rg;
          if (t < SEQ && j < DM)
            opb[t * OPLD + j] = f2h(fmaxf(acc[i][rg] + bias, 0.f));
        }
      }
    }
    __syncthreads();

    // ---- D: x[t][c] += cb2[c] + sum_j y2[t][j] cw2[j][c];  M=t(7) N=c(5) K=72(3) ----
    mfma_phase<5, 35, 3, 9>(opb, p.wf, base + 56, lane, wave, acc);
    __syncthreads();
    #pragma unroll
    for (int i = 0; i < 9; ++i) {
      int tile = wave + i * 4;
      if (tile < 35) {
        int mt = tile / 5, nt = tile % 5;
        int c = nt * 16 + m16;
        float bias = (c < DM) ? cb2[c] : 0.f;
        #pragma unroll
        for (int rg = 0; rg < 4; ++rg) {
          int t = mt * 16 + rowb + rg;
          if (t < SEQ && c < DM) {
            float xn = x_f32[t * XLD + c] + acc[i][rg] + bias;
            x_f32[t * XLD + c] = xn;
            opb[c * OPLD + t] = f2h(xn);   // xT for next resblock's A-step
          }
        }
      }
    }
    __syncthreads();
  }

  // ---- head (fp32 exact) ----
  if (tid < DM) {
    float a = 0.f;
    for (int t = 0; t < SEQ; ++t) a = fmaf(x_f32[t * XLD + tid], p.wp_time[t], a);
    sh[tid] = (a + p.bp_time[0]) * p.w_head[tid];
  }
  __syncthreads();
  if (tid == 0) {
    float yv = 0.f;
    #pragma unroll 8
    for (int i = 0; i < DM; ++i) yv += sh[i];
    yv = fmaxf(yv + p.b_head[0], 0.f);
    p.out[b]      = yv * s + hist_mean;
    p.out[NB + b] = s;
  }
}

extern "C" void kernel_launch(void* const* d_in, const int* in_sizes, int n_in,
                              void* d_out, int out_size, void* d_ws, size_t ws_size,
                              hipStream_t stream) {
  (void)in_sizes; (void)n_in; (void)out_size; (void)ws_size;

  SetupParams sp;
  sp.tw1[0] = (const float*)d_in[9];  sp.tw2[0] = (const float*)d_in[11];
  sp.cw1[0] = (const float*)d_in[13]; sp.cw2[0] = (const float*)d_in[15];
  sp.tw1[1] = (const float*)d_in[17]; sp.tw2[1] = (const float*)d_in[19];
  sp.cw1[1] = (const float*)d_in[21]; sp.cw2[1] = (const float*)d_in[23];
  sp.ws = (unsigned*)d_ws;
  hipLaunchKernelGGL(setup_kernel, dim3(TOTAL_SETS), dim3(256), 0, stream, sp);

  Params p;
  p.history   = (const float*)d_in[0];
  p.ts        = (const int*)  d_in[1];
  p.target_ts = (const int*)  d_in[2];
  p.task      = (const int*)  d_in[3];
  p.w_np = (const float*)d_in[4];  p.b_np = (const float*)d_in[5];
  p.w_wp = (const float*)d_in[6];  p.b_wp = (const float*)d_in[7];
  p.task_emb = (const float*)d_in[8];
  p.tb1[0] = (const float*)d_in[10]; p.tb2[0] = (const float*)d_in[12];
  p.cb1[0] = (const float*)d_in[14]; p.cb2[0] = (const float*)d_in[16];
  p.tb1[1] = (const float*)d_in[18]; p.tb2[1] = (const float*)d_in[20];
  p.cb1[1] = (const float*)d_in[22]; p.cb2[1] = (const float*)d_in[24];
  p.wp_time = (const float*)d_in[25]; p.bp_time = (const float*)d_in[26];
  p.w_head  = (const float*)d_in[27]; p.b_head  = (const float*)d_in[28];
  p.wf  = (const uint4*)d_ws;
  p.out = (float*)d_out;
  hipLaunchKernelGGL(fpfn_kernel, dim3(NB), dim3(256), 0, stream, p);
}

// Round 5
// 653.265 us; speedup vs baseline: 2.9111x; 1.3913x over previous
//
#include <hip/hip_runtime.h>
#include <math.h>

#define NB   8192
#define TLEN 100
#define SEQ  101
#define DE   36
#define DM   72
#define OPLD 104    // operand buffer row stride (fp16 elems); mult of 8 -> 16B-aligned b128
#define OPN  10496  // per-buffer element count (max read index 10495)
#define XLD  76     // x_f32 row stride (mult of 4 -> aligned float4; 76%32=12 -> 2-way max)

// frag sets per resblock: A:4k*5n=20, B:3*7=21, C:3*5=15, D:3*5=15 -> 71
#define RB_SETS    71
#define TOTAL_SETS 142
#define LO_V4      (TOTAL_SETS * 64)   // uint4 offset of lo-frag array in ws

typedef _Float16 half8v __attribute__((ext_vector_type(8)));
typedef __attribute__((ext_vector_type(4))) float f32x4;
union U16 { uint4 u; half8v h; };

#define MFMAH(a, b, c) __builtin_amdgcn_mfma_f32_16x16x32_f16((a), (b), (c), 0, 0, 0)

static __device__ __forceinline__ unsigned short f2h(float f) {
  union { _Float16 h; unsigned short u; } c;
  c.h = (_Float16)f;
  return c.u;
}

struct SetupParams {
  const float* tw1[2]; const float* tw2[2]; const float* cw1[2]; const float* cw2[2];
  unsigned* ws;
};

// Pack weights into MFMA B-fragment order as fp16 hi + fp16 lo (residual),
// zero-padded for k >= K and n >= N.  Slot bijection: k = kstep*32 + (lane>>4)*8 + e,
// n = ntile*16 + (lane&15); dword r holds elements e=2r (lo16) and e=2r+1 (hi16).
__global__ void setup_kernel(SetupParams sp) {
  int s = blockIdx.x;           // set id 0..141
  int tid = threadIdx.x;        // 256
  int l = tid >> 2, r = tid & 3;
  int rb = s / RB_SETS, s2 = s % RB_SETS;
  const float* W; int K, N, ks, nt;
  if (s2 < 20)      { ks = s2 / 5;        nt = s2 % 5;        W = sp.tw1[rb]; K = SEQ; N = DM; }
  else if (s2 < 41) { int t = s2 - 20; ks = t / 7; nt = t % 7; W = sp.tw2[rb]; K = DM;  N = SEQ; }
  else if (s2 < 56) { int t = s2 - 41; ks = t / 5; nt = t % 5; W = sp.cw1[rb]; K = DM;  N = DM; }
  else              { int t = s2 - 56; ks = t / 5; nt = t % 5; W = sp.cw2[rb]; K = DM;  N = DM; }
  int g = l >> 4;
  int n = nt * 16 + (l & 15);
  int k0 = ks * 32 + g * 8 + 2 * r;
  int k1 = k0 + 1;
  float f0 = (k0 < K && n < N) ? W[k0 * N + n] : 0.f;
  float f1 = (k1 < K && n < N) ? W[k1 * N + n] : 0.f;
  union { _Float16 h; unsigned short u; } h0, h1;
  h0.h = (_Float16)f0; h1.h = (_Float16)f1;
  unsigned short l0 = f2h(f0 - (float)h0.h), l1 = f2h(f1 - (float)h1.h);
  unsigned idx = (unsigned)s * 256u + (unsigned)l * 4u + (unsigned)r;
  sp.ws[idx] = (unsigned)h0.u | ((unsigned)h1.u << 16);
  sp.ws[(unsigned)TOTAL_SETS * 256u + idx] = (unsigned)l0 | ((unsigned)l1 << 16);
}

struct Params {
  const float *history; const int *ts; const int *target_ts; const int *task;
  const float *w_np; const float *b_np; const float *w_wp; const float *b_wp;
  const float *task_emb;
  const float *tb1[2]; const float *tb2[2]; const float *cb1[2]; const float *cb2[2];
  const float *wp_time; const float *bp_time; const float *w_head; const float *b_head;
  const uint4 *wf; float *out;
};

// GEMM phase: wave owns tiles wave, wave+4, ...  Straight-line (clamped dead
// slots recompute a valid tile; epilogue guards discard).  All KSTEPS loads
// batched before the MFMA chain so next tile's loads overlap current MFMAs.
template<int NTN, int NTILES, int KSTEPS, int MAXT>
static __device__ __forceinline__ void mfma_phase(
    const unsigned short* __restrict__ opb,
    const uint4* __restrict__ wf, int set_base, int lane, int wave, f32x4* acc) {
  const int g8 = (lane >> 4) * 8;
  const int m16 = lane & 15;
  #pragma unroll
  for (int i = 0; i < MAXT; ++i) {
    int tile = wave + i * 4; if (tile > NTILES - 1) tile = NTILES - 1;
    int mt = tile / NTN, nt = tile % NTN;
    int mrow = mt * 16 + m16; if (mrow > SEQ - 1) mrow = SEQ - 1;
    int abase = mrow * OPLD + g8;
    half8v ah[KSTEPS]; uint4 wh[KSTEPS], wl[KSTEPS];
    #pragma unroll
    for (int ks = 0; ks < KSTEPS; ++ks) {
      ah[ks] = *(const half8v*)&opb[abase + ks * 32];
      int set = set_base + ks * NTN + nt;
      wh[ks] = wf[(size_t)set * 64 + lane];
      wl[ks] = wf[(size_t)LO_V4 + (size_t)set * 64 + lane];
    }
    f32x4 a = {0.f, 0.f, 0.f, 0.f};
    #pragma unroll
    for (int ks = 0; ks < KSTEPS; ++ks) {
      U16 h; h.u = wh[ks]; U16 l; l.u = wl[ks];
      a = MFMAH(ah[ks], h.h, a);
      a = MFMAH(ah[ks], l.h, a);
    }
    acc[i] = a;
  }
}

__global__ __launch_bounds__(256, 2) void fpfn_kernel(Params p) {
  __shared__ __align__(16) unsigned short buf0[OPN];   // ping-pong fp16 operand buffers
  __shared__ __align__(16) unsigned short buf1[OPN];
  __shared__ __align__(16) float x_f32[SEQ * XLD];     // fp32 residual stream
  __shared__ float pe[640];
  __shared__ float sh[TLEN];
  __shared__ unsigned short datesu[TLEN * 4];

  const int tid  = threadIdx.x;
  const int b    = blockIdx.x;
  const int lane = tid & 63;
  const int wave = tid >> 6;

  // ---- zero operand buffers (pad regions must stay finite/zero) ----
  {
    uint4 z = {0, 0, 0, 0};
    uint4* z0 = (uint4*)buf0;
    uint4* z1 = (uint4*)buf1;
    for (int i = tid; i < OPN / 8; i += 256) { z0[i] = z; z1[i] = z; }
  }

  float s = 0.f, hist_mean = 0.f;   // valid in wave 0 (used by tid 0 at the end)

  if (wave == 0) {
    // ---- robust_scale entirely in one wave (no block barriers) ----
    int t1 = lane + 64;
    bool v1 = (t1 < TLEN);
    float h0 = p.history[(size_t)b * TLEN + lane];
    float h1 = v1 ? p.history[(size_t)b * TLEN + t1] : 0.f;
    auto wred = [&](float v) -> float {
      #pragma unroll
      for (int o = 32; o > 0; o >>= 1) v += __shfl_xor(v, o, 64);
      return v;
    };
    float nz0 = (h0 != 0.f) ? 1.f : 0.f;
    float nz1 = (v1 && h1 != 0.f) ? 1.f : 0.f;
    float cnt  = wred(nz0 + nz1);
    float hsum = wred(h0 + h1);
    float safe = fmaxf(cnt, 1.f);
    float mean = hsum / safe;
    float var  = wred(nz0 * (h0 - mean) * (h0 - mean) + nz1 * (h1 - mean) * (h1 - mean)) / safe;
    float mean_z = (cnt > 0.f) ? mean : 0.f;
    float std_z  = (cnt > 0.f) ? sqrtf(var) : 0.f;
    float upper  = mean_z + 2.f * std_z;
    float c0v = fminf(fmaxf(h0, 0.f), upper);
    float c1v = fminf(fmaxf(h1, 0.f), upper);
    float m0 = (c0v != 0.f) ? 1.f : 0.f;
    float m1 = (v1 && c1v != 0.f) ? 1.f : 0.f;
    float cnt2 = wred(m0 + m1);
    float csum = wred(m0 * c0v + m1 * c1v);
    float safe2 = fmaxf(cnt2, 1.f);
    float mc = csum / safe2;
    float vc = wred(m0 * (c0v - mc) * (c0v - mc) + m1 * (c1v - mc) * (c1v - mc)) / safe2;
    float mc_z = (cnt2 > 0.f) ? mc : 0.f;
    float sc_z = (cnt2 > 0.f) ? sqrtf(vc) : 0.f;
    s = mc_z + sc_z + 1e-4f;
    hist_mean = hsum * (1.f / (float)TLEN);
    sh[lane] = fminf(fmaxf(h0 / s, 0.f), 3.f);
    if (v1) sh[t1] = fminf(fmaxf(h1 / s, 0.f), 3.f);
  } else {
    // ---- waves 1-3: positional tables + date offsets ----
    for (int idx = tid - 64; idx < 640; idx += 192) {
      int periods, freqs, row, col;
      if (idx < 88)       { periods = 10; freqs = 4; row = idx >> 3;        col = idx & 7; }
      else if (idx < 192) { periods = 12; freqs = 4; row = (idx - 88) >> 3; col = (idx - 88) & 7; }
      else if (idx < 576) { periods = 31; freqs = 6; int r2 = idx - 192; row = r2 / 12; col = r2 - row * 12; }
      else                { periods = 7;  freqs = 4; row = (idx - 576) >> 3; col = (idx - 576) & 7; }
      int jf = (col < freqs) ? col : (col - freqs);
      float pip = (float)(3.14159265358979323846 / (double)periods);
      float ang = pip * (float)(1 << jf) * ((float)row - 1.0f);
      pe[idx] = (col < freqs) ? sinf(ang) : cosf(ang);
    }
    int t = tid - 64;
    if (t < TLEN) {
      int yr99 = p.ts[((size_t)b * TLEN + (TLEN - 1)) * 4 + 0];
      const int* tsb = p.ts + ((size_t)b * TLEN + t) * 4;
      int dy = yr99 - tsb[0]; dy = dy < 0 ? 0 : (dy > 10 ? 10 : dy);
      datesu[t * 4 + 0] = (unsigned short)(dy * 8);
      datesu[t * 4 + 1] = (unsigned short)(88  + tsb[1] * 8);
      datesu[t * 4 + 2] = (unsigned short)(192 + tsb[2] * 12);
      datesu[t * 4 + 3] = (unsigned short)(576 + tsb[3] * 8);
    }
  }
  __syncthreads();

  // ---- build x: f32 into x_f32[t][j], fp16 transposed into buf0[j][t] ----
  for (int idx = tid; idx < DM * TLEN; idx += 256) {
    int j = idx / TLEN;
    int t = idx - j * TLEN;
    float sv = sh[t];
    float v;
    if (j < DE) {
      v = fmaxf(fmaf(sv, p.w_np[j], p.b_np[j]), 0.f);
    } else {
      int jj = j - DE;
      float e1 = fmaxf(fmaf(sv, p.w_wp[jj], p.b_wp[jj]), 0.f);
      float pv;
      if (jj < 8)       pv = pe[datesu[t * 4 + 0] + jj];
      else if (jj < 16) pv = pe[datesu[t * 4 + 1] + (jj - 8)];
      else if (jj < 28) pv = pe[datesu[t * 4 + 2] + (jj - 16)];
      else              pv = pe[datesu[t * 4 + 3] + (jj - 28)];
      v = e1 + pv;
    }
    x_f32[t * XLD + j] = v;
    buf0[j * OPLD + t] = f2h(v);
  }
  if (tid < DM) {  // target row t=100
    int tk = p.task[b];
    float te = p.task_emb[tk * DE + (tid < DE ? tid : tid - DE)];
    float v = te;
    if (tid >= DE) {
      int jj = tid - DE;
      const int* tt = p.target_ts + (size_t)b * 5;
      int yr99 = p.ts[((size_t)b * TLEN + (TLEN - 1)) * 4 + 0];
      int dy = yr99 - tt[0]; dy = dy < 0 ? 0 : (dy > 10 ? 10 : dy);
      float qv;
      if (jj < 8)       qv = pe[dy * 8 + jj];
      else if (jj < 16) qv = pe[88  + tt[1] * 8  + (jj - 8)];
      else if (jj < 28) qv = pe[192 + tt[2] * 12 + (jj - 16)];
      else              qv = pe[576 + tt[3] * 8  + (jj - 28)];
      v = te + qv;
    }
    x_f32[(SEQ - 1) * XLD + tid] = v;
    buf0[tid * OPLD + (SEQ - 1)] = f2h(v);
  }
  __syncthreads();

  const int m16 = lane & 15;
  const int rowb = (lane >> 4) * 4;
  f32x4 acc[9];

  #pragma unroll 1
  for (int rb = 0; rb < 2; ++rb) {
    const int base = rb * RB_SETS;
    const float* tb1 = p.tb1[rb]; const float* tb2 = p.tb2[rb];
    const float* cb1 = p.cb1[rb]; const float* cb2 = p.cb2[rb];

    // ---- A: y1[c][j] = relu(tb1[j] + sum_t xT[c][t] tw1[t][j]);  src buf0, dst buf1 ----
    mfma_phase<5, 25, 4, 7>(buf0, p.wf, base + 0, lane, wave, acc);
    #pragma unroll
    for (int i = 0; i < 7; ++i) {
      int tile = wave + i * 4;
      if (tile < 25) {
        int mt = tile / 5, nt = tile % 5;
        int j = nt * 16 + m16;
        if (j < DM) {
          float bias = tb1[j];
          #pragma unroll
          for (int rg = 0; rg < 4; ++rg) {
            int c = mt * 16 + rowb + rg;
            if (c < DM) buf1[c * OPLD + j] = f2h(fmaxf(acc[i][rg] + bias, 0.f));
          }
        }
      }
    }
    __syncthreads();

    // ---- B: x[t][c] += tb2[t] + sum_j y1[c][j] tw2[j][t];  src buf1, dst buf0 ----
    mfma_phase<7, 35, 3, 9>(buf1, p.wf, base + 20, lane, wave, acc);
    #pragma unroll
    for (int i = 0; i < 9; ++i) {
      int tile = wave + i * 4;
      if (tile < 35) {
        int mt = tile / 7, nt = tile % 7;
        int t = nt * 16 + m16;
        int c0 = mt * 16 + rowb;
        if (t < SEQ && c0 < DM) {        // c0 mult of 4; DM mult of 4 -> no straddle
          float bias = tb2[t];
          float4 xo = *(const float4*)&x_f32[t * XLD + c0];
          float4 xn;
          xn.x = xo.x + acc[i][0] + bias;
          xn.y = xo.y + acc[i][1] + bias;
          xn.z = xo.z + acc[i][2] + bias;
          xn.w = xo.w + acc[i][3] + bias;
          *(float4*)&x_f32[t * XLD + c0] = xn;
          ushort4 hx;
          hx.x = f2h(xn.x); hx.y = f2h(xn.y); hx.z = f2h(xn.z); hx.w = f2h(xn.w);
          *(ushort4*)&buf0[t * OPLD + c0] = hx;
        }
      }
    }
    __syncthreads();

    // ---- C: y2[t][j] = relu(cb1[j] + sum_c x[t][c] cw1[c][j]);  src buf0, dst buf1 ----
    mfma_phase<5, 35, 3, 9>(buf0, p.wf, base + 41, lane, wave, acc);
    #pragma unroll
    for (int i = 0; i < 9; ++i) {
      int tile = wave + i * 4;
      if (tile < 35) {
        int mt = tile / 5, nt = tile % 5;
        int j = nt * 16 + m16;
        if (j < DM) {
          float bias = cb1[j];
          #pragma unroll
          for (int rg = 0; rg < 4; ++rg) {
            int t = mt * 16 + rowb + rg;
            if (t < SEQ) buf1[t * OPLD + j] = f2h(fmaxf(acc[i][rg] + bias, 0.f));
          }
        }
      }
    }
    __syncthreads();

    // ---- D: x[t][c] += cb2[c] + sum_j y2[t][j] cw2[j][c];  src buf1, dst buf0 (xT) ----
    mfma_phase<5, 35, 3, 9>(buf1, p.wf, base + 56, lane, wave, acc);
    #pragma unroll
    for (int i = 0; i < 9; ++i) {
      int tile = wave + i * 4;
      if (tile < 35) {
        int mt = tile / 5, nt = tile % 5;
        int c = nt * 16 + m16;
        int t0 = mt * 16 + rowb;
        if (c < DM && t0 < SEQ) {
          float bias = cb2[c];
          if (t0 + 3 < SEQ) {
            float x0 = x_f32[(t0 + 0) * XLD + c] + acc[i][0] + bias;
            float x1 = x_f32[(t0 + 1) * XLD + c] + acc[i][1] + bias;
            float x2 = x_f32[(t0 + 2) * XLD + c] + acc[i][2] + bias;
            float x3 = x_f32[(t0 + 3) * XLD + c] + acc[i][3] + bias;
            x_f32[(t0 + 0) * XLD + c] = x0;
            x_f32[(t0 + 1) * XLD + c] = x1;
            x_f32[(t0 + 2) * XLD + c] = x2;
            x_f32[(t0 + 3) * XLD + c] = x3;
            ushort4 hx;
            hx.x = f2h(x0); hx.y = f2h(x1); hx.z = f2h(x2); hx.w = f2h(x3);
            *(ushort4*)&buf0[c * OPLD + t0] = hx;   // xT for next resblock's A
          } else {
            #pragma unroll
            for (int rg = 0; rg < 4; ++rg) {
              int t = t0 + rg;
              if (t < SEQ) {
                float xn = x_f32[t * XLD + c] + acc[i][rg] + bias;
                x_f32[t * XLD + c] = xn;
                buf0[c * OPLD + t] = f2h(xn);
              }
            }
          }
        }
      }
    }
    __syncthreads();
  }

  // ---- head (fp32 exact) ----
  if (tid < DM) {
    float a = 0.f;
    for (int t = 0; t < SEQ; ++t) a = fmaf(x_f32[t * XLD + tid], p.wp_time[t], a);
    sh[tid] = (a + p.bp_time[0]) * p.w_head[tid];
  }
  __syncthreads();
  if (tid == 0) {
    float yv = 0.f;
    #pragma unroll 8
    for (int i = 0; i < DM; ++i) yv += sh[i];
    yv = fmaxf(yv + p.b_head[0], 0.f);
    p.out[b]      = yv * s + hist_mean;
    p.out[NB + b] = s;
  }
}

extern "C" void kernel_launch(void* const* d_in, const int* in_sizes, int n_in,
                              void* d_out, int out_size, void* d_ws, size_t ws_size,
                              hipStream_t stream) {
  (void)in_sizes; (void)n_in; (void)out_size; (void)ws_size;

  SetupParams sp;
  sp.tw1[0] = (const float*)d_in[9];  sp.tw2[0] = (const float*)d_in[11];
  sp.cw1[0] = (const float*)d_in[13]; sp.cw2[0] = (const float*)d_in[15];
  sp.tw1[1] = (const float*)d_in[17]; sp.tw2[1] = (const float*)d_in[19];
  sp.cw1[1] = (const float*)d_in[21]; sp.cw2[1] = (const float*)d_in[23];
  sp.ws = (unsigned*)d_ws;
  hipLaunchKernelGGL(setup_kernel, dim3(TOTAL_SETS), dim3(256), 0, stream, sp);

  Params p;
  p.history   = (const float*)d_in[0];
  p.ts        = (const int*)  d_in[1];
  p.target_ts = (const int*)  d_in[2];
  p.task      = (const int*)  d_in[3];
  p.w_np = (const float*)d_in[4];  p.b_np = (const float*)d_in[5];
  p.w_wp = (const float*)d_in[6];  p.b_wp = (const float*)d_in[7];
  p.task_emb = (const float*)d_in[8];
  p.tb1[0] = (const float*)d_in[10]; p.tb2[0] = (const float*)d_in[12];
  p.cb1[0] = (const float*)d_in[14]; p.cb2[0] = (const float*)d_in[16];
  p.tb1[1] = (const float*)d_in[18]; p.tb2[1] = (const float*)d_in[20];
  p.cb1[1] = (const float*)d_in[22]; p.cb2[1] = (const float*)d_in[24];
  p.wp_time = (const float*)d_in[25]; p.bp_time = (const float*)d_in[26];
  p.w_head  = (const float*)d_in[27]; p.b_head  = (const float*)d_in[28];
  p.wf  = (const uint4*)d_ws;
  p.out = (float*)d_out;
  hipLaunchKernelGGL(fpfn_kernel, dim3(NB), dim3(256), 0, stream, p);
}